// Round 4
// baseline (260.879 us; speedup 1.0000x reference)
//
#include <hip/hip_runtime.h>
#include <math.h>

// ClusterisedSelfAttentionNotLearnable — R10: decoupled 1-wave blocks, M=64,
// spill-proofed.
// R9 post-mortem: 268 MB HBM traffic (WRITE 169 MB vs 2.4 MB output) at
// 2.3 TB/s == the whole 117us: register spill. The fully-unrolled 15-tile
// loop let the scheduler hoist B loads past the (64,3) ~170-VGPR cap
// (VGPR_Count=84 => allocator gave up). Structure itself was good
// (occ 17->28%, conflicts 375K->25K).
// R10: (a) outer d-loop unrolled (static part[] indexing), inner 5-tile loop
// ROLLED (#pragma unroll 1) so only one tile of B loads is ever in flight;
// (b) __launch_bounds__(64,2) -> 256-VGPR cap; (c) M=64 per wave (4 m-tiles):
// halves aggregate B traffic (750->375 MB) and doubles MFMA per B byte.
// Zero barriers; B read straight from global (L2-resident 120 KB).

#define NCLUST   256
#define M_BLK    64
#define THREADS  64
#define NTILES   15
#define BG_BYTES (NTILES * 8 * 64 * 16)   // 122880
#define ET_STRIDE 136                      // bytes/e-row: 64 pts * 2B + 8B pad

typedef __attribute__((ext_vector_type(8))) short bfrag_t;        // 8 bf16
typedef __attribute__((ext_vector_type(4))) float cfrag_t;        // 4 f32
typedef __attribute__((ext_vector_type(4))) unsigned int uifrag_t; // A-frag storage

static __device__ __forceinline__ unsigned short f2bf1(float f) {
    return __builtin_bit_cast(unsigned short, (__bf16)f);   // RNE, v_cvt_pk_bf16_f32
}
static __device__ __forceinline__ unsigned int f2bf2(float lo, float hi) {
    return (unsigned int)f2bf1(lo) | ((unsigned int)f2bf1(hi) << 16);
}
static __device__ __forceinline__ float bf2f(unsigned short s) {
    return __uint_as_float(((unsigned int)s) << 16);
}

// Build W' in fragment order: unit u -> (tile=u>>9, ks=(u>>6)&7, lane=u&63),
// lane=(q=lane>>4, ln=lane&15); holds W'[j'=tile*16+ln][c=ks*32+q*8 .. +8].
// W'[j'][c] = (e<72) ? W[(c*3+d)*72+e] : 0, with d=j'/80, e=j'-80d.
__global__ void prep_kernel(const float* __restrict__ W, uint4* __restrict__ Bg) {
    const int u = blockIdx.x * 256 + threadIdx.x;
    if (u >= NTILES * 8 * 64) return;
    const int lane = u & 63, ks = (u >> 6) & 7, tile = u >> 9;
    const int ln = lane & 15, q = lane >> 4;
    const int jp = tile * 16 + ln;
    const int d  = jp / 80;
    const int e  = jp - d * 80;
    const int c0 = ks * 32 + q * 8;
    unsigned int w[4] = {0u, 0u, 0u, 0u};
    if (e < 72) {
#pragma unroll
        for (int i = 0; i < 4; ++i) {
            float f0 = W[((c0 + 2 * i)     * 3 + d) * 72 + e];
            float f1 = W[((c0 + 2 * i + 1) * 3 + d) * 72 + e];
            w[i] = f2bf2(f0, f1);
        }
    }
    Bg[u] = make_uint4(w[0], w[1], w[2], w[3]);
}

__global__ __launch_bounds__(THREADS, 2) void rgb_attn_mfma(
    const float* __restrict__ X,
    const float* __restrict__ cent,
    const void* __restrict__ Bg,
    float* __restrict__ out, int N)
{
    __shared__ __align__(16) unsigned char encT[80 * ET_STRIDE];  // 10880 B, [e][point]

    const int lane = threadIdx.x;          // one wave per block
    const int q    = lane >> 4;
    const int ln   = lane & 15;

    // ---- positional encoding into encT (transposed): 1 thread/point, 6 dims ----
    {
        const int gpt = blockIdx.x * M_BLK + lane;
        const int gp  = (gpt < N) ? gpt : (N - 1);
        const float2 e01 = *(const float2*)(X + gp * 6);
        const float2 e23 = *(const float2*)(X + gp * 6 + 2);
        const float2 e45 = *(const float2*)(X + gp * 6 + 4);
        const float xs[6] = { e01.x, e01.y, e23.x, e23.y, e45.x, e45.y };
        unsigned char* colp = encT + lane * 2;
#pragma unroll
        for (int dd = 0; dd < 6; ++dd) {
            const float xv = xs[dd];
            float s[6], c[6];
            __sincosf(xv, &s[0], &c[0]);
#pragma unroll
            for (int f = 1; f < 6; ++f) {            // exact double-angle identities
                s[f] = 2.0f * s[f-1] * c[f-1];
                c[f] = 1.0f - 2.0f * s[f-1] * s[f-1];
            }
#pragma unroll
            for (int f = 0; f < 6; ++f) {
                *(unsigned short*)(colp + (dd*12 + f)     * ET_STRIDE) = f2bf1(s[f]);
                *(unsigned short*)(colp + (dd*12 + 6 + f) * ET_STRIDE) = f2bf1(c[f]);
            }
        }
        // zero pad rows e in [72,80): contiguous 1088 B region, 136 x 8B slots
#pragma unroll
        for (int i = lane; i < 136; i += 64)
            *(uint2*)(encT + 72 * ET_STRIDE + i * 8) = make_uint2(0u, 0u);
    }

    // ---- attention: A-fragments directly in registers, 4 m-tiles ----
    // Lane (q,ln) feeds MFMA rows mt*16+ln with clusters 32*g + q*8 + {0..7}.
    uifrag_t afrag[4][8];
    float den[4] = {0.f, 0.f, 0.f, 0.f};
    {
        float2 xy[4]; float zz[4];
#pragma unroll
        for (int mt = 0; mt < 4; ++mt) {
            const int ga = blockIdx.x * M_BLK + mt * 16 + ln;
            const int g  = (ga < N) ? ga : (N - 1);
            xy[mt] = *(const float2*)(X + g * 6);
            zz[mt] = X[g * 6 + 2];
        }
        const float4* c4base = (const float4*)cent;
#pragma unroll
        for (int g = 0; g < 8; ++g) {
            // 8 cent rows 32g + q*8 .. +8  ==  6 aligned float4
            const float4* c4 = c4base + (6 * q + 24 * g);
            const float4 v0 = c4[0], v1 = c4[1], v2 = c4[2];
            const float4 v3 = c4[3], v4 = c4[4], v5 = c4[5];
            float cx[8], cy[8], cz[8];
            cx[0]=v0.x; cy[0]=v0.y; cz[0]=v0.z;
            cx[1]=v0.w; cy[1]=v1.x; cz[1]=v1.y;
            cx[2]=v1.z; cy[2]=v1.w; cz[2]=v2.x;
            cx[3]=v2.y; cy[3]=v2.z; cz[3]=v2.w;
            cx[4]=v3.x; cy[4]=v3.y; cz[4]=v3.z;
            cx[5]=v3.w; cy[5]=v4.x; cz[5]=v4.y;
            cx[6]=v4.z; cy[6]=v4.w; cz[6]=v5.x;
            cx[7]=v5.y; cy[7]=v5.z; cz[7]=v5.w;
#pragma unroll
            for (int mt = 0; mt < 4; ++mt) {
                float e[8];
#pragma unroll
                for (int j = 0; j < 8; ++j) {
                    e[j] = __expf(fmaf(xy[mt].x, cx[j],
                                  fmaf(xy[mt].y, cy[j], zz[mt] * cz[j])));
                    den[mt] += e[j];
                }
#pragma unroll
                for (int w = 0; w < 4; ++w)
                    afrag[mt][g][w] = f2bf2(e[2*w], e[2*w+1]);
            }
        }
    }

    // ---- main loop: d unrolled (static part idx), 5-tile inner loop ROLLED
    //      so only one tile of B loads is in flight (spill-proof) ----
    const char* Bgc = (const char*)Bg + lane * 16;
    float part[3][4][4] = {};
#pragma unroll
    for (int d = 0; d < 3; ++d) {
#pragma unroll 1
        for (int tt = 0; tt < 5; ++tt) {
            const char* bp = Bgc + (d * 5 + tt) * 8192;
            bfrag_t b[8];
#pragma unroll
            for (int ks = 0; ks < 8; ++ks)
                b[ks] = *(const bfrag_t*)(bp + ks * 1024);
            cfrag_t a0 = {0.f,0.f,0.f,0.f}, a1 = {0.f,0.f,0.f,0.f};
            cfrag_t a2 = {0.f,0.f,0.f,0.f}, a3 = {0.f,0.f,0.f,0.f};
#pragma unroll
            for (int ks = 0; ks < 8; ++ks) {
                a0 = __builtin_amdgcn_mfma_f32_16x16x32_bf16(
                         __builtin_bit_cast(bfrag_t, afrag[0][ks]), b[ks], a0, 0, 0, 0);
                a1 = __builtin_amdgcn_mfma_f32_16x16x32_bf16(
                         __builtin_bit_cast(bfrag_t, afrag[1][ks]), b[ks], a1, 0, 0, 0);
                a2 = __builtin_amdgcn_mfma_f32_16x16x32_bf16(
                         __builtin_bit_cast(bfrag_t, afrag[2][ks]), b[ks], a2, 0, 0, 0);
                a3 = __builtin_amdgcn_mfma_f32_16x16x32_bf16(
                         __builtin_bit_cast(bfrag_t, afrag[3][ks]), b[ks], a3, 0, 0, 0);
            }
            const unsigned char* ep = encT + (tt * 16 + ln) * ET_STRIDE + q * 8;
#pragma unroll
            for (int mt = 0; mt < 4; ++mt) {
                const ushort4 ev = *(const ushort4*)(ep + mt * 32);
                const cfrag_t a = (mt == 0) ? a0 : (mt == 1) ? a1 : (mt == 2) ? a2 : a3;
                part[d][mt][0] = fmaf(a[0], bf2f(ev.x), part[d][mt][0]);
                part[d][mt][1] = fmaf(a[1], bf2f(ev.y), part[d][mt][1]);
                part[d][mt][2] = fmaf(a[2], bf2f(ev.z), part[d][mt][2]);
                part[d][mt][3] = fmaf(a[3], bf2f(ev.w), part[d][mt][3]);
            }
        }
    }

    // ---- reduce across the 16 e-lanes ----
#pragma unroll
    for (int mask = 1; mask <= 8; mask <<= 1)
#pragma unroll
        for (int d = 0; d < 3; ++d)
#pragma unroll
            for (int mt = 0; mt < 4; ++mt)
#pragma unroll
                for (int r = 0; r < 4; ++r)
                    part[d][mt][r] += __shfl_xor(part[d][mt][r], mask, 64);

    // ---- denominators: sum the 4 q-quarters, invert, gather per output row ----
    float invr[4][4];
#pragma unroll
    for (int mt = 0; mt < 4; ++mt) {
        den[mt] += __shfl_xor(den[mt], 16, 64);
        den[mt] += __shfl_xor(den[mt], 32, 64);
        const float iv = 1.0f / den[mt];     // denom of point mt*16+ln (all q)
#pragma unroll
        for (int r = 0; r < 4; ++r)          // lane q*4+r holds denom of pt mt*16+q*4+r
            invr[mt][r] = __shfl(iv, q * 4 + r, 64);
    }

    if (ln == 0) {
#pragma unroll
        for (int mt = 0; mt < 4; ++mt)
#pragma unroll
            for (int r = 0; r < 4; ++r) {
                const int pm = mt * 16 + q * 4 + r;
                const int g  = blockIdx.x * M_BLK + pm;
                if (g < N) {
                    out[g*3+0] = part[0][mt][r] * invr[mt][r];
                    out[g*3+1] = part[1][mt][r] * invr[mt][r];
                    out[g*3+2] = part[2][mt][r] * invr[mt][r];
                }
            }
    }
}

// ---- fallback (correct, slow) if d_ws too small ----
__global__ __launch_bounds__(256) void rgb_attn_fallback(
    const float* __restrict__ X, const float* __restrict__ W,
    const float* __restrict__ cent, float* __restrict__ out, int N)
{
    const int n = blockIdx.x * 256 + threadIdx.x;
    const bool valid = (n < N);
    float x[6];
#pragma unroll
    for (int k = 0; k < 6; ++k) x[k] = valid ? X[n * 6 + k] : 0.0f;
    float enc[72];
#pragma unroll
    for (int d = 0; d < 6; ++d)
#pragma unroll
        for (int f = 0; f < 6; ++f) {
            float s, c;
            __sincosf(x[d] * (float)(1 << f), &s, &c);
            enc[d*12+f] = s; enc[d*12+6+f] = c;
        }
    float acc0 = 0, acc1 = 0, acc2 = 0, denom = 0;
#pragma unroll 1
    for (int c = 0; c < NCLUST; ++c) {
        float s = fmaf(x[0], cent[c*3], fmaf(x[1], cent[c*3+1], x[2]*cent[c*3+2]));
        float ew = __expf(s);
        const float* w = W + c * 216;
        float d0 = 0, d1 = 0, d2 = 0;
#pragma unroll
        for (int e = 0; e < 72; ++e) {
            float ee = enc[e];
            d0 = fmaf(ee, w[e], d0);
            d1 = fmaf(ee, w[72 + e], d1);
            d2 = fmaf(ee, w[144 + e], d2);
        }
        denom += ew;
        acc0 = fmaf(ew, d0, acc0); acc1 = fmaf(ew, d1, acc1); acc2 = fmaf(ew, d2, acc2);
    }
    if (valid) {
        float inv = 1.0f / denom;
        out[n*3+0] = acc0*inv; out[n*3+1] = acc1*inv; out[n*3+2] = acc2*inv;
    }
}

extern "C" void kernel_launch(void* const* d_in, const int* in_sizes, int n_in,
                              void* d_out, int out_size, void* d_ws, size_t ws_size,
                              hipStream_t stream)
{
    const float* X    = (const float*)d_in[0];   // [N, 6]
    const float* W    = (const float*)d_in[1];   // [768, 72]
    const float* cent = (const float*)d_in[2];   // [256, 3]
    float* out = (float*)d_out;                  // [N, 3]
    const int N = in_sizes[0] / 6;

    if (ws_size >= (size_t)BG_BYTES) {
        uint4* Bg = (uint4*)d_ws;
        prep_kernel<<<(NTILES * 8 * 64 + 255) / 256, 256, 0, stream>>>(W, Bg);
        const int blocks = (N + M_BLK - 1) / M_BLK;
        rgb_attn_mfma<<<blocks, THREADS, 0, stream>>>(X, cent, (const void*)Bg, out, N);
    } else {
        rgb_attn_fallback<<<(N + 255) / 256, 256, 0, stream>>>(X, W, cent, out, N);
    }
}

// Round 5
// 114.617 us; speedup vs baseline: 2.2761x; 2.2761x over previous
//
#include <hip/hip_runtime.h>
#include <math.h>

// ClusterisedSelfAttentionNotLearnable — R11: decoupled 1-wave blocks, M=32,
// register budget sized with slack.
// R9/R10 post-mortem: both spilled (WRITE_SIZE 169/203 MB vs 2.4 MB output).
// VGPR_Count evidence (84 under (64,3), 128 under (64,2)) + m69's occupancy
// steps at 64/128/256 => waves/SIMD is quantized {1,2,4,8}; (64,3) silently
// became a 128-reg budget, and M=64's ~250-reg demand overflowed (64,2)'s
// 256 minus the AGPR carve-out. Structure itself was validated (occ 17->28%,
// conflicts 375K->25K).
// R11: M=32/wave => afrag 64 VGPR, total demand ~158 vs 256 budget at (64,2)
// (~100 regs slack). d-loop unrolled (static part idx), inner 5-tile loop
// ROLLED so only one tile of B is in flight. Zero barriers; B straight from
// global (120 KB, L2-resident); encT per-wave LDS (5.8 KB).
// Floors: B L2 traffic 750 MB ~22us; MFMA ~10us.

#define NCLUST   256
#define M_BLK    32
#define THREADS  64
#define NTILES   15
#define BG_BYTES (NTILES * 8 * 64 * 16)   // 122880
#define ET_STRIDE 72                       // bytes/e-row: 32 pts * 2B + 8B pad

typedef __attribute__((ext_vector_type(8))) short bfrag_t;        // 8 bf16
typedef __attribute__((ext_vector_type(4))) float cfrag_t;        // 4 f32
typedef __attribute__((ext_vector_type(4))) unsigned int uifrag_t; // A-frag storage

static __device__ __forceinline__ unsigned short f2bf1(float f) {
    return __builtin_bit_cast(unsigned short, (__bf16)f);   // RNE, v_cvt_pk_bf16_f32
}
static __device__ __forceinline__ unsigned int f2bf2(float lo, float hi) {
    return (unsigned int)f2bf1(lo) | ((unsigned int)f2bf1(hi) << 16);
}
static __device__ __forceinline__ float bf2f(unsigned short s) {
    return __uint_as_float(((unsigned int)s) << 16);
}

// Build W' in fragment order: unit u -> (tile=u>>9, ks=(u>>6)&7, lane=u&63),
// lane=(q=lane>>4, ln=lane&15); holds W'[j'=tile*16+ln][c=ks*32+q*8 .. +8].
// W'[j'][c] = (e<72) ? W[(c*3+d)*72+e] : 0, with d=j'/80, e=j'-80d.
__global__ void prep_kernel(const float* __restrict__ W, uint4* __restrict__ Bg) {
    const int u = blockIdx.x * 256 + threadIdx.x;
    if (u >= NTILES * 8 * 64) return;
    const int lane = u & 63, ks = (u >> 6) & 7, tile = u >> 9;
    const int ln = lane & 15, q = lane >> 4;
    const int jp = tile * 16 + ln;
    const int d  = jp / 80;
    const int e  = jp - d * 80;
    const int c0 = ks * 32 + q * 8;
    unsigned int w[4] = {0u, 0u, 0u, 0u};
    if (e < 72) {
#pragma unroll
        for (int i = 0; i < 4; ++i) {
            float f0 = W[((c0 + 2 * i)     * 3 + d) * 72 + e];
            float f1 = W[((c0 + 2 * i + 1) * 3 + d) * 72 + e];
            w[i] = f2bf2(f0, f1);
        }
    }
    Bg[u] = make_uint4(w[0], w[1], w[2], w[3]);
}

__global__ __launch_bounds__(THREADS, 2) void rgb_attn_mfma(
    const float* __restrict__ X,
    const float* __restrict__ cent,
    const void* __restrict__ Bg,
    float* __restrict__ out, int N)
{
    __shared__ __align__(16) unsigned char encT[80 * ET_STRIDE];  // 5760 B, [e][point]

    const int lane = threadIdx.x;          // one wave per block
    const int q    = lane >> 4;
    const int ln   = lane & 15;

    // ---- positional encoding into encT (transposed): 2 threads/point, 3 dims each ----
    {
        const int pt  = lane & 31;
        const int h   = lane >> 5;
        const int gpt = blockIdx.x * M_BLK + pt;
        const int gp  = (gpt < N) ? gpt : (N - 1);
        unsigned char* colp = encT + pt * 2;
#pragma unroll
        for (int k = 0; k < 3; ++k) {
            const int dd = 3 * h + k;
            const float xv = X[gp * 6 + dd];
            float s[6], c[6];
            __sincosf(xv, &s[0], &c[0]);
#pragma unroll
            for (int f = 1; f < 6; ++f) {            // exact double-angle identities
                s[f] = 2.0f * s[f-1] * c[f-1];
                c[f] = 1.0f - 2.0f * s[f-1] * s[f-1];
            }
#pragma unroll
            for (int f = 0; f < 6; ++f) {
                *(unsigned short*)(colp + (dd*12 + f)     * ET_STRIDE) = f2bf1(s[f]);
                *(unsigned short*)(colp + (dd*12 + 6 + f) * ET_STRIDE) = f2bf1(c[f]);
            }
        }
        // zero pad rows e in [72,80): 8 rows x 64B, 8 threads/row x 8B
        *(uint2*)(encT + (72 + (lane >> 3)) * ET_STRIDE + (lane & 7) * 8) = make_uint2(0u, 0u);
    }

    // ---- attention: A-fragments directly in registers (verified lane map) ----
    // Lane (q,ln) feeds MFMA rows mt*16+ln with clusters 32*g + q*8 + {0..7}.
    uifrag_t afrag[2][8];
    float dA = 0.0f, dB = 0.0f;
    {
        const int g0a = blockIdx.x * M_BLK + ln;
        const int g0  = (g0a < N) ? g0a : (N - 1);
        const int g1a = g0a + 16;
        const int g1  = (g1a < N) ? g1a : (N - 1);
        const float2 xy0 = *(const float2*)(X + g0 * 6);
        const float  z0  = X[g0 * 6 + 2];
        const float2 xy1 = *(const float2*)(X + g1 * 6);
        const float  z1  = X[g1 * 6 + 2];
        const float4* c4base = (const float4*)cent;
#pragma unroll
        for (int g = 0; g < 8; ++g) {
            // 8 cent rows 32g + q*8 .. +8  ==  6 aligned float4
            const float4* c4 = c4base + (6 * q + 24 * g);
            const float4 v0 = c4[0], v1 = c4[1], v2 = c4[2];
            const float4 v3 = c4[3], v4 = c4[4], v5 = c4[5];
            float cx[8], cy[8], cz[8];
            cx[0]=v0.x; cy[0]=v0.y; cz[0]=v0.z;
            cx[1]=v0.w; cy[1]=v1.x; cz[1]=v1.y;
            cx[2]=v1.z; cy[2]=v1.w; cz[2]=v2.x;
            cx[3]=v2.y; cy[3]=v2.z; cz[3]=v2.w;
            cx[4]=v3.x; cy[4]=v3.y; cz[4]=v3.z;
            cx[5]=v3.w; cy[5]=v4.x; cz[5]=v4.y;
            cx[6]=v4.z; cy[6]=v4.w; cz[6]=v5.x;
            cx[7]=v5.y; cy[7]=v5.z; cz[7]=v5.w;
            float ea[8], eb[8];
#pragma unroll
            for (int j = 0; j < 8; ++j) {
                ea[j] = __expf(fmaf(xy0.x, cx[j], fmaf(xy0.y, cy[j], z0 * cz[j])));
                eb[j] = __expf(fmaf(xy1.x, cx[j], fmaf(xy1.y, cy[j], z1 * cz[j])));
                dA += ea[j]; dB += eb[j];
            }
#pragma unroll
            for (int w = 0; w < 4; ++w) {
                afrag[0][g][w] = f2bf2(ea[2*w], ea[2*w+1]);
                afrag[1][g][w] = f2bf2(eb[2*w], eb[2*w+1]);
            }
        }
    }

    // ---- main loop: d unrolled (static part idx), 5-tile inner loop ROLLED
    //      so only one tile of B loads is in flight (spill-proof) ----
    const char* Bgc = (const char*)Bg + lane * 16;
    float part[3][2][4] = {};
#pragma unroll
    for (int d = 0; d < 3; ++d) {
#pragma unroll 1
        for (int tt = 0; tt < 5; ++tt) {
            const char* bp = Bgc + (d * 5 + tt) * 8192;
            bfrag_t b[8];
#pragma unroll
            for (int ks = 0; ks < 8; ++ks)
                b[ks] = *(const bfrag_t*)(bp + ks * 1024);
            cfrag_t a0 = {0.f,0.f,0.f,0.f}, a1 = {0.f,0.f,0.f,0.f};
#pragma unroll
            for (int ks = 0; ks < 8; ++ks) {
                a0 = __builtin_amdgcn_mfma_f32_16x16x32_bf16(
                         __builtin_bit_cast(bfrag_t, afrag[0][ks]), b[ks], a0, 0, 0, 0);
                a1 = __builtin_amdgcn_mfma_f32_16x16x32_bf16(
                         __builtin_bit_cast(bfrag_t, afrag[1][ks]), b[ks], a1, 0, 0, 0);
            }
            const unsigned char* ep = encT + (tt * 16 + ln) * ET_STRIDE + q * 8;
#pragma unroll
            for (int mt = 0; mt < 2; ++mt) {
                const ushort4 ev = *(const ushort4*)(ep + mt * 32);
                const cfrag_t a = mt ? a1 : a0;
                part[d][mt][0] = fmaf(a[0], bf2f(ev.x), part[d][mt][0]);
                part[d][mt][1] = fmaf(a[1], bf2f(ev.y), part[d][mt][1]);
                part[d][mt][2] = fmaf(a[2], bf2f(ev.z), part[d][mt][2]);
                part[d][mt][3] = fmaf(a[3], bf2f(ev.w), part[d][mt][3]);
            }
        }
    }

    // ---- reduce across the 16 e-lanes ----
#pragma unroll
    for (int mask = 1; mask <= 8; mask <<= 1)
#pragma unroll
        for (int d = 0; d < 3; ++d)
#pragma unroll
            for (int mt = 0; mt < 2; ++mt)
#pragma unroll
                for (int r = 0; r < 4; ++r)
                    part[d][mt][r] += __shfl_xor(part[d][mt][r], mask, 64);

    // ---- denominators: sum the 4 q-quarters, invert, gather per output row ----
    dA += __shfl_xor(dA, 16, 64); dA += __shfl_xor(dA, 32, 64);
    dB += __shfl_xor(dB, 16, 64); dB += __shfl_xor(dB, 32, 64);
    const float iA = 1.0f / dA;          // denom of point ln (all q-lanes)
    const float iB = 1.0f / dB;          // denom of point 16+ln
    float invr[2][4];
#pragma unroll
    for (int r = 0; r < 4; ++r) {        // lane q*4+r holds denom of point q*4+r
        invr[0][r] = __shfl(iA, q * 4 + r, 64);
        invr[1][r] = __shfl(iB, q * 4 + r, 64);
    }

    if (ln == 0) {
#pragma unroll
        for (int mt = 0; mt < 2; ++mt)
#pragma unroll
            for (int r = 0; r < 4; ++r) {
                const int pm = mt * 16 + q * 4 + r;
                const int g  = blockIdx.x * M_BLK + pm;
                if (g < N) {
                    out[g*3+0] = part[0][mt][r] * invr[mt][r];
                    out[g*3+1] = part[1][mt][r] * invr[mt][r];
                    out[g*3+2] = part[2][mt][r] * invr[mt][r];
                }
            }
    }
}

// ---- fallback (correct, slow) if d_ws too small ----
__global__ __launch_bounds__(256) void rgb_attn_fallback(
    const float* __restrict__ X, const float* __restrict__ W,
    const float* __restrict__ cent, float* __restrict__ out, int N)
{
    const int n = blockIdx.x * 256 + threadIdx.x;
    const bool valid = (n < N);
    float x[6];
#pragma unroll
    for (int k = 0; k < 6; ++k) x[k] = valid ? X[n * 6 + k] : 0.0f;
    float enc[72];
#pragma unroll
    for (int d = 0; d < 6; ++d)
#pragma unroll
        for (int f = 0; f < 6; ++f) {
            float s, c;
            __sincosf(x[d] * (float)(1 << f), &s, &c);
            enc[d*12+f] = s; enc[d*12+6+f] = c;
        }
    float acc0 = 0, acc1 = 0, acc2 = 0, denom = 0;
#pragma unroll 1
    for (int c = 0; c < NCLUST; ++c) {
        float s = fmaf(x[0], cent[c*3], fmaf(x[1], cent[c*3+1], x[2]*cent[c*3+2]));
        float ew = __expf(s);
        const float* w = W + c * 216;
        float d0 = 0, d1 = 0, d2 = 0;
#pragma unroll
        for (int e = 0; e < 72; ++e) {
            float ee = enc[e];
            d0 = fmaf(ee, w[e], d0);
            d1 = fmaf(ee, w[72 + e], d1);
            d2 = fmaf(ee, w[144 + e], d2);
        }
        denom += ew;
        acc0 = fmaf(ew, d0, acc0); acc1 = fmaf(ew, d1, acc1); acc2 = fmaf(ew, d2, acc2);
    }
    if (valid) {
        float inv = 1.0f / denom;
        out[n*3+0] = acc0*inv; out[n*3+1] = acc1*inv; out[n*3+2] = acc2*inv;
    }
}

extern "C" void kernel_launch(void* const* d_in, const int* in_sizes, int n_in,
                              void* d_out, int out_size, void* d_ws, size_t ws_size,
                              hipStream_t stream)
{
    const float* X    = (const float*)d_in[0];   // [N, 6]
    const float* W    = (const float*)d_in[1];   // [768, 72]
    const float* cent = (const float*)d_in[2];   // [256, 3]
    float* out = (float*)d_out;                  // [N, 3]
    const int N = in_sizes[0] / 6;

    if (ws_size >= (size_t)BG_BYTES) {
        uint4* Bg = (uint4*)d_ws;
        prep_kernel<<<(NTILES * 8 * 64 + 255) / 256, 256, 0, stream>>>(W, Bg);
        const int blocks = (N + M_BLK - 1) / M_BLK;
        rgb_attn_mfma<<<blocks, THREADS, 0, stream>>>(X, cent, (const void*)Bg, out, N);
    } else {
        rgb_attn_fallback<<<(N + 255) / 256, 256, 0, stream>>>(X, W, cent, out, N);
    }
}